// Round 12
// baseline (341.220 us; speedup 1.0000x reference)
//
#include <hip/hip_runtime.h>
#include <cstdint>
#include <cstddef>

// GIN 2-layer + mean-pool + head. bf16 features (row-major), fp32 accum.
// Structure: detect(+zeroing) -> fused prep (bucket 8192-chunks + converts +
// goff) -> per-bucket LDS counting sort -> high-occupancy gather kernels
// (x8-unrolled, no LDS) -> fused MLP kernels (GEMM1 -> LDS tile -> GEMM2,
// MFMA bf16). Conv2's MLP fuses mean-pool (block-level reduction; R10:
// 100k device fp32 atomics on 32 lines = serialization wall) and the final
// head via a last-block done-counter.

namespace {

constexpr int N_NODES  = 100000;
constexpr int N_EDGES  = 1600000;
constexpr int N_GRAPHS = 512;
constexpr int NBUCK    = (N_NODES + 511) / 512;   // 196 dst-range buckets
constexpr int BCAP     = 9216;   // per-bucket edge capacity (avg 8163, +11 sigma)

constexpr size_t algn(size_t x){ return (x + size_t(255)) & ~size_t(255); }

constexpr size_t OFF_CNT   = 0;                                        // N ints
constexpr size_t OFF_ROW   = algn(OFF_CNT   + size_t(N_NODES)*4);      // N ints
constexpr size_t OFF_GOFF  = algn(OFF_ROW   + size_t(N_NODES)*4);      // 513 ints
constexpr size_t OFF_FLAG  = algn(OFF_GOFF  + 513*4);                  // 1 int
constexpr size_t OFF_DONE  = algn(OFF_FLAG  + 4);                      // 1 int
constexpr size_t OFF_GCUR  = algn(OFF_DONE  + 4);                      // NBUCK ints
constexpr size_t OFF_PACC  = algn(OFF_GCUR  + size_t(NBUCK)*4);        // 512 f32
constexpr size_t OFF_BKT   = algn(OFF_PACC  + 512*4);                  // NBUCK*BCAP u32
constexpr size_t OFF_CSR   = algn(OFF_BKT   + size_t(NBUCK)*BCAP*4);   // NBUCK*BCAP u32
constexpr size_t OFF_XB    = algn(OFF_CSR   + size_t(NBUCK)*BCAP*4);   // N*64 bf16
constexpr size_t OFF_WT1A  = algn(OFF_XB    + size_t(N_NODES)*64*2);   // 128*64 bf16
constexpr size_t OFF_WT1B  = algn(OFF_WT1A  + 8192*2);                 // 128*128 bf16
constexpr size_t OFF_WT2A  = algn(OFF_WT1B  + 16384*2);
constexpr size_t OFF_WT2B  = algn(OFF_WT2A  + 16384*2);
constexpr size_t OFF_F0    = algn(OFF_WT2B  + 16384*2);                // N*64 bf16
constexpr size_t OFF_H1    = algn(OFF_F0    + size_t(N_NODES)*64*2);   // N*128 bf16
constexpr size_t OFF_H2    = algn(OFF_H1    + size_t(N_NODES)*128*2);  // N*128 bf16
constexpr size_t WS_NEED   = OFF_H2 + size_t(N_NODES)*128*2;           // ~92 MB

// prep-kernel block partition (bucket blocks first: their LDS-atomic latency
// overlaps the streaming converts). 8192-edge chunks halve the global
// reservation atomics on gcur (R11 analysis: 77k RMWs on ~13 lines).
constexpr int PB_BUCKET = (N_EDGES + 8191) / 8192;          // 196
constexpr int PB_CVTX   = (N_NODES * 64 / 4 + 255) / 256;   // 6250
constexpr int PB_CVTW   = 224;
constexpr int PB_TOTAL  = PB_BUCKET + PB_CVTX + PB_CVTW + 1;

// ---- helpers ---------------------------------------------------------------
__device__ __forceinline__ int load_idx(const void* p, size_t i, bool wide) {
    return wide ? (int)((const long long*)p)[i] : ((const int*)p)[i];
}

__device__ __forceinline__ uint16_t f32_to_bf16(float f) {
    union { float f; uint32_t i; } v; v.f = f;
    uint32_t u = v.i;
    uint32_t r = (u + 0x7FFFu + ((u >> 16) & 1u)) >> 16;   // RNE
    return (uint16_t)r;
}

__device__ __forceinline__ void unpack2(uint32_t u, float& a, float& b) {
    union { uint32_t i; float f; } x, y;
    x.i = u << 16;            // low half  = elem 0
    y.i = u & 0xFFFF0000u;    // high half = elem 1
    a = x.f; b = y.f;
}

__device__ __forceinline__ uint32_t pack2(float a, float b) {
    return (uint32_t)f32_to_bf16(a) | ((uint32_t)f32_to_bf16(b) << 16);
}

__device__ __forceinline__ void accum8(float* a, uint4 w) {
    float b0, b1;
    unpack2(w.x, b0, b1); a[0] += b0; a[1] += b1;
    unpack2(w.y, b0, b1); a[2] += b0; a[3] += b1;
    unpack2(w.z, b0, b1); a[4] += b0; a[5] += b1;
    unpack2(w.w, b0, b1); a[6] += b0; a[7] += b1;
}

// ---- index width detection + scratch zeroing -------------------------------
// int64 layout -> every odd 32-bit word (high half) is 0. flag==0 -> wide.
__global__ void detect_wide(const int* __restrict__ ei, int* __restrict__ flag,
                            int* __restrict__ gcur, float* __restrict__ pacc,
                            int* __restrict__ done) {
    const int tid = threadIdx.x;
    if (tid < NBUCK) gcur[tid] = 0;
    for (int i = tid; i < N_GRAPHS; i += 256) pacc[i] = 0.f;
    if (tid == 0) { *flag = 0; *done = 0; }
    __syncthreads();
    int v = ei[2 * tid + 1];
    if (v != 0) atomicOr(flag, 1);
}

// ---- fused prep: bucket_edges | cvt_x | cvt_weights | goff_search ----------
__global__ void prep(const void* __restrict__ ei, const void* __restrict__ bat,
                     const int* __restrict__ flag,
                     const float* __restrict__ x,
                     const float* __restrict__ W1a, const float* __restrict__ W1b,
                     const float* __restrict__ W2a, const float* __restrict__ W2b,
                     int* __restrict__ gcur, uint32_t* __restrict__ bkt,
                     uint16_t* __restrict__ xb,
                     uint16_t* __restrict__ T1a, uint16_t* __restrict__ T1b,
                     uint16_t* __restrict__ T2a, uint16_t* __restrict__ T2b,
                     int* __restrict__ goff) {
    __shared__ int lcnt[NBUCK];
    __shared__ int lbase[NBUCK];
    const int bx  = blockIdx.x;
    const int tid = threadIdx.x;
    const bool wide = (*flag == 0);

    if (bx < PB_BUCKET) {
        // ---- partition edges into dst-range buckets, packed src<<9|dstl ----
        for (int i = tid; i < NBUCK; i += 256) lcnt[i] = 0;
        __syncthreads();
        int es[32], ed[32], er[32];
        const int base = bx * 8192;
        #pragma unroll
        for (int i = 0; i < 32; ++i) {
            int e = base + i * 256 + tid;
            if (e < N_EDGES) {
                es[i] = load_idx(ei, size_t(e), wide);
                ed[i] = load_idx(ei, size_t(N_EDGES) + e, wide);
                er[i] = atomicAdd(&lcnt[ed[i] >> 9], 1);
            } else ed[i] = -1;
        }
        __syncthreads();
        for (int i = tid; i < NBUCK; i += 256)
            lbase[i] = atomicAdd(&gcur[i], lcnt[i]);
        __syncthreads();
        #pragma unroll
        for (int i = 0; i < 32; ++i) {
            if (ed[i] < 0) continue;
            int b = ed[i] >> 9;
            int idx = lbase[b] + er[i];
            if (idx < BCAP)
                bkt[size_t(b) * BCAP + idx] =
                    ((uint32_t)es[i] << 9) | (uint32_t)(ed[i] & 511);
        }
    } else if (bx < PB_BUCKET + PB_CVTX) {
        // ---- x fp32 -> bf16, 4 floats/thread ----
        size_t i = (size_t)((bx - PB_BUCKET) * 256 + tid) * 4;
        float4 f = *reinterpret_cast<const float4*>(&x[i]);
        uint2 o = make_uint2(pack2(f.x, f.y), pack2(f.z, f.w));
        *reinterpret_cast<uint2*>(&xb[i]) = o;
    } else if (bx < PB_BUCKET + PB_CVTX + PB_CVTW) {
        // ---- transpose W[K][128] fp32 -> WT[n*K+k] bf16 ----
        int idx = (bx - PB_BUCKET - PB_CVTX) * 256 + tid;   // 57344 total
        const float* W; uint16_t* T; int K; int local;
        if (idx < 8192)        { W = W1a; T = T1a; K = 64;  local = idx; }
        else if (idx < 24576)  { W = W1b; T = T1b; K = 128; local = idx - 8192; }
        else if (idx < 40960)  { W = W2a; T = T2a; K = 128; local = idx - 24576; }
        else                   { W = W2b; T = T2b; K = 128; local = idx - 40960; }
        int k = local >> 7, n = local & 127;
        T[n * K + k] = f32_to_bf16(W[local]);
    } else {
        // ---- graph offsets via binary search (batch is sorted) ----
        for (int g = tid; g <= N_GRAPHS; g += 256) {
            int lo = 0, hi = N_NODES;
            while (lo < hi) {
                int mid = (lo + hi) >> 1;
                if (load_idx(bat, size_t(mid), wide) < g) lo = mid + 1; else hi = mid;
            }
            goff[g] = lo;
        }
    }
}

// ---- per-bucket LDS counting sort -> dense dst-sorted CSR (512 thr) --------
__launch_bounds__(512)
__global__ void sort_bucket(const uint32_t* __restrict__ bkt, const int* __restrict__ gcur,
                            uint32_t* __restrict__ csr, int* __restrict__ row,
                            int* __restrict__ cnt) {
    __shared__ int h[512];
    __shared__ int cur[512];
    __shared__ int sd[512];
    const int b = blockIdx.x, tid = threadIdx.x;
    int n = gcur[b]; n = n > BCAP ? BCAP : n;
    const uint32_t* eb = bkt + size_t(b) * BCAP;
    h[tid] = 0;
    __syncthreads();
    for (int i = tid; i < n; i += 512) atomicAdd(&h[eb[i] & 511u], 1);
    __syncthreads();
    const int a0 = h[tid];
    sd[tid] = a0;
    __syncthreads();
    for (int off = 1; off < 512; off <<= 1) {
        int t = (tid >= off) ? sd[tid - off] : 0;
        __syncthreads();
        sd[tid] += t;
        __syncthreads();
    }
    const int base = sd[tid] - a0;     // exclusive prefix
    cur[tid] = base;
    const int node = b * 512 + tid;
    if (node < N_NODES) {
        row[node] = b * BCAP + base;
        cnt[node] = a0;
    }
    __syncthreads();
    uint32_t* cb = csr + size_t(b) * BCAP;
    for (int i = tid; i < n; i += 512) {
        uint32_t e = eb[i];
        int p = atomicAdd(&cur[e & 511u], 1);
        cb[p] = e >> 9;
    }
}

// ---- aggregation: out[i] = x[i] + sum_{j->i} x[j]  (bf16 in/out, fp32 acc) -
// Neighbor loop unrolled x8 with independent loads -> 8x memory-level
// parallelism. No LDS: occupancy is the gather's lifeblood (R8 lesson).
template <int D>
__global__ void gin_aggregate(const uint16_t* __restrict__ xb, const int* __restrict__ row,
                              const int* __restrict__ cnt, const uint32_t* __restrict__ csr,
                              uint16_t* __restrict__ out) {
    constexpr int TPN = D / 8;                 // lanes per node (16B bf16 each)
    const int tid  = threadIdx.x;
    const int node = blockIdx.x * (256 / TPN) + tid / TPN;
    const int lane = tid % TPN;
    if (node >= N_NODES) return;
    const size_t off   = size_t(lane) * 8;
    const size_t rbase = size_t(node) * D + off;
    uint4 v = *reinterpret_cast<const uint4*>(&xb[rbase]);
    float a[8];
    unpack2(v.x, a[0], a[1]); unpack2(v.y, a[2], a[3]);
    unpack2(v.z, a[4], a[5]); unpack2(v.w, a[6], a[7]);
    const int c = cnt[node];
    const uint32_t* sl = csr + row[node];
    int p = 0;
    for (; p + 8 <= c; p += 8) {
        uint4 w0 = *reinterpret_cast<const uint4*>(&xb[size_t(sl[p + 0]) * D + off]);
        uint4 w1 = *reinterpret_cast<const uint4*>(&xb[size_t(sl[p + 1]) * D + off]);
        uint4 w2 = *reinterpret_cast<const uint4*>(&xb[size_t(sl[p + 2]) * D + off]);
        uint4 w3 = *reinterpret_cast<const uint4*>(&xb[size_t(sl[p + 3]) * D + off]);
        uint4 w4 = *reinterpret_cast<const uint4*>(&xb[size_t(sl[p + 4]) * D + off]);
        uint4 w5 = *reinterpret_cast<const uint4*>(&xb[size_t(sl[p + 5]) * D + off]);
        uint4 w6 = *reinterpret_cast<const uint4*>(&xb[size_t(sl[p + 6]) * D + off]);
        uint4 w7 = *reinterpret_cast<const uint4*>(&xb[size_t(sl[p + 7]) * D + off]);
        accum8(a, w0); accum8(a, w1); accum8(a, w2); accum8(a, w3);
        accum8(a, w4); accum8(a, w5); accum8(a, w6); accum8(a, w7);
    }
    for (; p < c; ++p) {
        uint4 w = *reinterpret_cast<const uint4*>(&xb[size_t(sl[p]) * D + off]);
        accum8(a, w);
    }
    uint4 o = make_uint4(pack2(a[0], a[1]), pack2(a[2], a[3]),
                         pack2(a[4], a[5]), pack2(a[6], a[7]));
    *reinterpret_cast<uint4*>(&out[rbase]) = o;
}

// ---- fused conv MLP: relu( relu(A@Wa + ba) @ Wb + bb ) ---------------------
// POOL=false: coalesced stores to out. POOL=true: per-row dot(Wc) + shfl
// reduce -> LDS -> per-graph LDS reduce -> ~2-3 global atomics per block;
// the LAST block (device done-counter, acq-rel) computes the final head.
// launch_bounds(256,3): (256,4) caps VGPR at 64 -> scratch spill (R9/R10).
typedef __attribute__((ext_vector_type(8))) short short8;
typedef __attribute__((ext_vector_type(4))) float f32x4;

template <int K1, bool POOL>
__launch_bounds__(256, 3)
__global__ void gin_mlp(const uint16_t* __restrict__ A, const uint16_t* __restrict__ WTa,
                        const float* __restrict__ ba, const uint16_t* __restrict__ WTb,
                        const float* __restrict__ bb, uint16_t* __restrict__ out,
                        const void* __restrict__ bat, const int* __restrict__ flag,
                        const float* __restrict__ Wc, float* __restrict__ pacc,
                        const int* __restrict__ goff, const float* __restrict__ bc,
                        float* __restrict__ head, int* __restrict__ done,
                        int M) {
    constexpr int TSTR = 136;                       // +8 halfword pad
    __shared__ uint16_t tile[128 * TSTR];           // 34 KB
    const int tid  = threadIdx.x;
    const int wave = tid >> 6;
    const int lane = tid & 63;
    const int lr   = lane & 15;
    const int q    = lane >> 4;
    const int bnode0 = blockIdx.x * 128;
    const int m_base = bnode0 + wave * 32;
    const int trow   = wave * 32 + q * 4;           // first output row (local)

    // ---- GEMM1: A @ WTa -> tile (bias ba, relu) ----
    short8 afr1[2][K1 / 32];
    #pragma unroll
    for (int mt = 0; mt < 2; ++mt) {
        int row = m_base + mt * 16 + lr;
        row = row < M ? row : (M - 1);
        const uint16_t* ap = A + size_t(row) * K1 + q * 8;
        #pragma unroll
        for (int kb = 0; kb < K1 / 32; ++kb)
            afr1[mt][kb] = *reinterpret_cast<const short8*>(ap + kb * 32);
    }
    for (int nt = 0; nt < 8; ++nt) {
        const uint16_t* bp = WTa + size_t(nt * 16 + lr) * K1 + q * 8;
        f32x4 c0 = {0.f, 0.f, 0.f, 0.f};
        f32x4 c1 = {0.f, 0.f, 0.f, 0.f};
        #pragma unroll
        for (int kb = 0; kb < K1 / 32; ++kb) {
            short8 b = *reinterpret_cast<const short8*>(bp + kb * 32);
            c0 = __builtin_amdgcn_mfma_f32_16x16x32_bf16(afr1[0][kb], b, c0, 0, 0, 0);
            c1 = __builtin_amdgcn_mfma_f32_16x16x32_bf16(afr1[1][kb], b, c1, 0, 0, 0);
        }
        const float bv = ba[nt * 16 + lr];
        const int col = nt * 16 + lr;
        #pragma unroll
        for (int r = 0; r < 4; ++r) {
            float v0 = fmaxf(c0[r] + bv, 0.f);
            float v1 = fmaxf(c1[r] + bv, 0.f);
            tile[(trow + r) * TSTR + col]      = f32_to_bf16(v0);
            tile[(trow + 16 + r) * TSTR + col] = f32_to_bf16(v1);
        }
    }
    __syncthreads();

    // ---- A-fragments for GEMM2 from LDS tile ----
    short8 afr2[2][4];
    #pragma unroll
    for (int mt = 0; mt < 2; ++mt) {
        const int r = wave * 32 + mt * 16 + lr;
        #pragma unroll
        for (int kb = 0; kb < 4; ++kb)
            afr2[mt][kb] = *reinterpret_cast<const short8*>(
                &tile[r * TSTR + kb * 32 + q * 8]);
    }
    __syncthreads();   // tile is dead after this; reused below

    // ---- GEMM2 (bias bb, relu) ----
    if (!POOL) {
        for (int nt = 0; nt < 8; ++nt) {
            const uint16_t* bp = WTb + size_t(nt * 16 + lr) * 128 + q * 8;
            f32x4 c0 = {0.f, 0.f, 0.f, 0.f};
            f32x4 c1 = {0.f, 0.f, 0.f, 0.f};
            #pragma unroll
            for (int kb = 0; kb < 4; ++kb) {
                short8 b = *reinterpret_cast<const short8*>(bp + kb * 32);
                c0 = __builtin_amdgcn_mfma_f32_16x16x32_bf16(afr2[0][kb], b, c0, 0, 0, 0);
                c1 = __builtin_amdgcn_mfma_f32_16x16x32_bf16(afr2[1][kb], b, c1, 0, 0, 0);
            }
            const float bv = bb[nt * 16 + lr];
            const int col = nt * 16 + lr;
            #pragma unroll
            for (int r = 0; r < 4; ++r) {
                float v0 = fmaxf(c0[r] + bv, 0.f);
                float v1 = fmaxf(c1[r] + bv, 0.f);
                tile[(trow + r) * TSTR + col]      = f32_to_bf16(v0);
                tile[(trow + 16 + r) * TSTR + col] = f32_to_bf16(v1);
            }
        }
        __syncthreads();
        // coalesced vectorized stores: 16 threads per row, 16B each
        const int c8 = (tid & 15) * 8;
        for (int rr = tid >> 4; rr < 128; rr += 16) {
            int grow = bnode0 + rr;
            if (grow < M)
                *reinterpret_cast<uint4*>(&out[size_t(grow) * 128 + c8]) =
                    *reinterpret_cast<const uint4*>(&tile[rr * TSTR + c8]);
        }
    } else {
        // block-level pooled reduction (tile memory reused as fp32 scratch)
        float* rowdot = reinterpret_cast<float*>(tile);        // [0..128)
        float* gacc   = rowdot + 128;                          // [128..256)
        if (tid < 128) gacc[tid] = 0.f;

        float pd0[4] = {0.f, 0.f, 0.f, 0.f};
        float pd1[4] = {0.f, 0.f, 0.f, 0.f};
        for (int nt = 0; nt < 8; ++nt) {
            const uint16_t* bp = WTb + size_t(nt * 16 + lr) * 128 + q * 8;
            f32x4 c0 = {0.f, 0.f, 0.f, 0.f};
            f32x4 c1 = {0.f, 0.f, 0.f, 0.f};
            #pragma unroll
            for (int kb = 0; kb < 4; ++kb) {
                short8 b = *reinterpret_cast<const short8*>(bp + kb * 32);
                c0 = __builtin_amdgcn_mfma_f32_16x16x32_bf16(afr2[0][kb], b, c0, 0, 0, 0);
                c1 = __builtin_amdgcn_mfma_f32_16x16x32_bf16(afr2[1][kb], b, c1, 0, 0, 0);
            }
            const int col = nt * 16 + lr;
            const float bv = bb[col];
            const float wv = Wc[col];
            #pragma unroll
            for (int r = 0; r < 4; ++r) {
                pd0[r] += fmaxf(c0[r] + bv, 0.f) * wv;
                pd1[r] += fmaxf(c1[r] + bv, 0.f) * wv;
            }
        }
        #pragma unroll
        for (int m = 1; m < 16; m <<= 1) {
            #pragma unroll
            for (int r = 0; r < 4; ++r) {
                pd0[r] += __shfl_xor(pd0[r], m, 64);
                pd1[r] += __shfl_xor(pd1[r], m, 64);
            }
        }
        if (lr == 0) {
            #pragma unroll
            for (int r = 0; r < 4; ++r) {
                rowdot[trow + r]      = pd0[r];
                rowdot[trow + 16 + r] = pd1[r];
            }
        }
        __syncthreads();

        const bool wide = (*flag == 0);
        const int g0 = load_idx(bat, size_t(bnode0 < M ? bnode0 : M - 1), wide);
        if (tid < 128) {
            int node = bnode0 + tid;
            if (node < M) {
                int g = load_idx(bat, size_t(node), wide);
                int idx = g - g0;
                if (idx < 128) atomicAdd(&gacc[idx], rowdot[tid]);
                else           atomicAdd(&pacc[g], rowdot[tid]);   // gap fallback
            }
        }
        __syncthreads();
        int last = bnode0 + 127 < M ? bnode0 + 127 : M - 1;
        int span = load_idx(bat, size_t(last), wide) - g0;
        if (span > 127) span = 127;
        if (tid <= span) {
            float v = gacc[tid];
            if (v != 0.f) atomicAdd(&pacc[g0 + tid], v);
        }

        // ---- last block computes the head (saves a launch) ----
        __shared__ int lastflag;
        __threadfence();
        if (tid == 0) {
            int v = __hip_atomic_fetch_add(done, 1, __ATOMIC_ACQ_REL,
                                           __HIP_MEMORY_SCOPE_AGENT);
            lastflag = (v == (int)gridDim.x - 1);
        }
        __syncthreads();
        if (lastflag) {
            for (int g = tid; g < N_GRAPHS; g += 256) {
                float v = __hip_atomic_load(&pacc[g], __ATOMIC_RELAXED,
                                            __HIP_MEMORY_SCOPE_AGENT);
                int c = goff[g + 1] - goff[g];
                float denom = (c > 0) ? (float)c : 1.f;
                head[g] = v / denom + bc[0];
            }
        }
    }
}

}  // namespace

extern "C" void kernel_launch(void* const* d_in, const int* in_sizes, int n_in,
                              void* d_out, int out_size, void* d_ws, size_t ws_size,
                              hipStream_t stream) {
    (void)in_sizes; (void)n_in; (void)out_size;
    if (ws_size < WS_NEED) return;

    const float* x   = (const float*)d_in[0];
    const void*  ei  = d_in[1];
    const void*  bat = d_in[2];
    const float* W1a = (const float*)d_in[3];
    const float* b1a = (const float*)d_in[4];
    const float* W1b = (const float*)d_in[5];
    const float* b1b = (const float*)d_in[6];
    const float* W2a = (const float*)d_in[7];
    const float* b2a = (const float*)d_in[8];
    const float* W2b = (const float*)d_in[9];
    const float* b2b = (const float*)d_in[10];
    const float* Wc  = (const float*)d_in[11];
    const float* bc  = (const float*)d_in[12];
    float* out = (float*)d_out;

    char* ws = (char*)d_ws;
    int*      cnt  = (int*)(ws + OFF_CNT);
    int*      row  = (int*)(ws + OFF_ROW);
    int*      goff = (int*)(ws + OFF_GOFF);
    int*      flg  = (int*)(ws + OFF_FLAG);
    int*      done = (int*)(ws + OFF_DONE);
    int*      gcur = (int*)(ws + OFF_GCUR);
    float*    pacc = (float*)(ws + OFF_PACC);
    uint32_t* bkt  = (uint32_t*)(ws + OFF_BKT);
    uint32_t* csr  = (uint32_t*)(ws + OFF_CSR);
    uint16_t* xb   = (uint16_t*)(ws + OFF_XB);
    uint16_t* T1a  = (uint16_t*)(ws + OFF_WT1A);
    uint16_t* T1b  = (uint16_t*)(ws + OFF_WT1B);
    uint16_t* T2a  = (uint16_t*)(ws + OFF_WT2A);
    uint16_t* T2b  = (uint16_t*)(ws + OFF_WT2B);
    uint16_t* F0   = (uint16_t*)(ws + OFF_F0);
    uint16_t* H1   = (uint16_t*)(ws + OFF_H1);
    uint16_t* H2   = (uint16_t*)(ws + OFF_H2);

    detect_wide<<<1, 256, 0, stream>>>((const int*)ei, flg, gcur, pacc, done);

    // fused prep: bucket + cvt_x + cvt_weights + goff
    prep<<<PB_TOTAL, 256, 0, stream>>>(ei, bat, flg, x, W1a, W1b, W2a, W2b,
                                       gcur, bkt, xb, T1a, T1b, T2a, T2b, goff);
    sort_bucket<<<NBUCK, 512, 0, stream>>>(bkt, gcur, csr, row, cnt);

    constexpr int GRID = (N_NODES + 127) / 128;   // 782

    // conv1
    gin_aggregate<64><<<(N_NODES + 31) / 32, 256, 0, stream>>>(xb, row, cnt, csr, F0);
    gin_mlp<64, false><<<GRID, 256, 0, stream>>>(F0, T1a, b1a, T1b, b1b, H1,
                                                 bat, flg, Wc, pacc, goff, bc,
                                                 out, done, N_NODES);
    // conv2 (MLP fuses mean-pool + last-block head)
    gin_aggregate<128><<<(N_NODES + 15) / 16, 256, 0, stream>>>(H1, row, cnt, csr, H2);
    gin_mlp<128, true><<<GRID, 256, 0, stream>>>(H2, T2a, b2a, T2b, b2b, H1,
                                                 bat, flg, Wc, pacc, goff, bc,
                                                 out, done, N_NODES);
}

// Round 13
// 293.547 us; speedup vs baseline: 1.1624x; 1.1624x over previous
//
#include <hip/hip_runtime.h>
#include <cstdint>
#include <cstddef>

// GIN 2-layer + mean-pool + head. bf16 features (row-major), fp32 accum.
// Structure (R11-proven, 299us): detect(+zeroing) -> fused prep (bucket
// 4096-chunks + converts + goff) -> per-bucket LDS counting sort ->
// high-occupancy gather kernels (x8-unrolled, no LDS) -> fused MLP kernels
// (GEMM1 -> LDS tile -> GEMM2, MFMA bf16; conv2 fuses mean-pool via
// block-level reduction) -> tiny finalize.
// R12 lessons: NO per-block __threadfence (O(blocks) drain >> one 3us
// launch); NO 32-deep per-thread arrays in prep (VGPR spill).

namespace {

constexpr int N_NODES  = 100000;
constexpr int N_EDGES  = 1600000;
constexpr int N_GRAPHS = 512;
constexpr int NBUCK    = (N_NODES + 511) / 512;   // 196 dst-range buckets
constexpr int BCAP     = 9216;   // per-bucket edge capacity (avg 8163, +11 sigma)

constexpr size_t algn(size_t x){ return (x + size_t(255)) & ~size_t(255); }

constexpr size_t OFF_CNT   = 0;                                        // N ints
constexpr size_t OFF_ROW   = algn(OFF_CNT   + size_t(N_NODES)*4);      // N ints
constexpr size_t OFF_GOFF  = algn(OFF_ROW   + size_t(N_NODES)*4);      // 513 ints
constexpr size_t OFF_FLAG  = algn(OFF_GOFF  + 513*4);                  // 1 int
constexpr size_t OFF_GCUR  = algn(OFF_FLAG  + 4);                      // NBUCK ints
constexpr size_t OFF_PACC  = algn(OFF_GCUR  + size_t(NBUCK)*4);        // 512 f32
constexpr size_t OFF_BKT   = algn(OFF_PACC  + 512*4);                  // NBUCK*BCAP u32
constexpr size_t OFF_CSR   = algn(OFF_BKT   + size_t(NBUCK)*BCAP*4);   // NBUCK*BCAP u32
constexpr size_t OFF_XB    = algn(OFF_CSR   + size_t(NBUCK)*BCAP*4);   // N*64 bf16
constexpr size_t OFF_WT1A  = algn(OFF_XB    + size_t(N_NODES)*64*2);   // 128*64 bf16
constexpr size_t OFF_WT1B  = algn(OFF_WT1A  + 8192*2);                 // 128*128 bf16
constexpr size_t OFF_WT2A  = algn(OFF_WT1B  + 16384*2);
constexpr size_t OFF_WT2B  = algn(OFF_WT2A  + 16384*2);
constexpr size_t OFF_F0    = algn(OFF_WT2B  + 16384*2);                // N*64 bf16
constexpr size_t OFF_H1    = algn(OFF_F0    + size_t(N_NODES)*64*2);   // N*128 bf16
constexpr size_t OFF_H2    = algn(OFF_H1    + size_t(N_NODES)*128*2);  // N*128 bf16
constexpr size_t WS_NEED   = OFF_H2 + size_t(N_NODES)*128*2;           // ~92 MB

// prep-kernel block partition (bucket blocks first: their LDS-atomic latency
// overlaps the streaming converts)
constexpr int PB_BUCKET = (N_EDGES + 4095) / 4096;          // 391
constexpr int PB_CVTX   = (N_NODES * 64 / 4 + 255) / 256;   // 6250
constexpr int PB_CVTW   = 224;
constexpr int PB_TOTAL  = PB_BUCKET + PB_CVTX + PB_CVTW + 1;

// ---- helpers ---------------------------------------------------------------
__device__ __forceinline__ int load_idx(const void* p, size_t i, bool wide) {
    return wide ? (int)((const long long*)p)[i] : ((const int*)p)[i];
}

__device__ __forceinline__ uint16_t f32_to_bf16(float f) {
    union { float f; uint32_t i; } v; v.f = f;
    uint32_t u = v.i;
    uint32_t r = (u + 0x7FFFu + ((u >> 16) & 1u)) >> 16;   // RNE
    return (uint16_t)r;
}

__device__ __forceinline__ void unpack2(uint32_t u, float& a, float& b) {
    union { uint32_t i; float f; } x, y;
    x.i = u << 16;            // low half  = elem 0
    y.i = u & 0xFFFF0000u;    // high half = elem 1
    a = x.f; b = y.f;
}

__device__ __forceinline__ uint32_t pack2(float a, float b) {
    return (uint32_t)f32_to_bf16(a) | ((uint32_t)f32_to_bf16(b) << 16);
}

__device__ __forceinline__ void accum8(float* a, uint4 w) {
    float b0, b1;
    unpack2(w.x, b0, b1); a[0] += b0; a[1] += b1;
    unpack2(w.y, b0, b1); a[2] += b0; a[3] += b1;
    unpack2(w.z, b0, b1); a[4] += b0; a[5] += b1;
    unpack2(w.w, b0, b1); a[6] += b0; a[7] += b1;
}

// ---- index width detection + scratch zeroing -------------------------------
// int64 layout -> every odd 32-bit word (high half) is 0. flag==0 -> wide.
__global__ void detect_wide(const int* __restrict__ ei, int* __restrict__ flag,
                            int* __restrict__ gcur, float* __restrict__ pacc) {
    const int tid = threadIdx.x;
    if (tid < NBUCK) gcur[tid] = 0;
    for (int i = tid; i < N_GRAPHS; i += 256) pacc[i] = 0.f;
    if (tid == 0) *flag = 0;
    __syncthreads();
    int v = ei[2 * tid + 1];
    if (v != 0) atomicOr(flag, 1);
}

// ---- fused prep: bucket_edges | cvt_x | cvt_weights | goff_search ----------
__global__ void prep(const void* __restrict__ ei, const void* __restrict__ bat,
                     const int* __restrict__ flag,
                     const float* __restrict__ x,
                     const float* __restrict__ W1a, const float* __restrict__ W1b,
                     const float* __restrict__ W2a, const float* __restrict__ W2b,
                     int* __restrict__ gcur, uint32_t* __restrict__ bkt,
                     uint16_t* __restrict__ xb,
                     uint16_t* __restrict__ T1a, uint16_t* __restrict__ T1b,
                     uint16_t* __restrict__ T2a, uint16_t* __restrict__ T2b,
                     int* __restrict__ goff) {
    __shared__ int lcnt[NBUCK];
    __shared__ int lbase[NBUCK];
    const int bx  = blockIdx.x;
    const int tid = threadIdx.x;
    const bool wide = (*flag == 0);

    if (bx < PB_BUCKET) {
        // ---- partition edges into dst-range buckets, packed src<<9|dstl ----
        for (int i = tid; i < NBUCK; i += 256) lcnt[i] = 0;
        __syncthreads();
        int es[16], ed[16], er[16];
        const int base = bx * 4096;
        #pragma unroll
        for (int i = 0; i < 16; ++i) {
            int e = base + i * 256 + tid;
            if (e < N_EDGES) {
                es[i] = load_idx(ei, size_t(e), wide);
                ed[i] = load_idx(ei, size_t(N_EDGES) + e, wide);
                er[i] = atomicAdd(&lcnt[ed[i] >> 9], 1);
            } else ed[i] = -1;
        }
        __syncthreads();
        for (int i = tid; i < NBUCK; i += 256)
            lbase[i] = atomicAdd(&gcur[i], lcnt[i]);
        __syncthreads();
        #pragma unroll
        for (int i = 0; i < 16; ++i) {
            if (ed[i] < 0) continue;
            int b = ed[i] >> 9;
            int idx = lbase[b] + er[i];
            if (idx < BCAP)
                bkt[size_t(b) * BCAP + idx] =
                    ((uint32_t)es[i] << 9) | (uint32_t)(ed[i] & 511);
        }
    } else if (bx < PB_BUCKET + PB_CVTX) {
        // ---- x fp32 -> bf16, 4 floats/thread ----
        size_t i = (size_t)((bx - PB_BUCKET) * 256 + tid) * 4;
        float4 f = *reinterpret_cast<const float4*>(&x[i]);
        uint2 o = make_uint2(pack2(f.x, f.y), pack2(f.z, f.w));
        *reinterpret_cast<uint2*>(&xb[i]) = o;
    } else if (bx < PB_BUCKET + PB_CVTX + PB_CVTW) {
        // ---- transpose W[K][128] fp32 -> WT[n*K+k] bf16 ----
        int idx = (bx - PB_BUCKET - PB_CVTX) * 256 + tid;   // 57344 total
        const float* W; uint16_t* T; int K; int local;
        if (idx < 8192)        { W = W1a; T = T1a; K = 64;  local = idx; }
        else if (idx < 24576)  { W = W1b; T = T1b; K = 128; local = idx - 8192; }
        else if (idx < 40960)  { W = W2a; T = T2a; K = 128; local = idx - 24576; }
        else                   { W = W2b; T = T2b; K = 128; local = idx - 40960; }
        int k = local >> 7, n = local & 127;
        T[n * K + k] = f32_to_bf16(W[local]);
    } else {
        // ---- graph offsets via binary search (batch is sorted) ----
        for (int g = tid; g <= N_GRAPHS; g += 256) {
            int lo = 0, hi = N_NODES;
            while (lo < hi) {
                int mid = (lo + hi) >> 1;
                if (load_idx(bat, size_t(mid), wide) < g) lo = mid + 1; else hi = mid;
            }
            goff[g] = lo;
        }
    }
}

// ---- per-bucket LDS counting sort -> dense dst-sorted CSR (512 thr) --------
__launch_bounds__(512)
__global__ void sort_bucket(const uint32_t* __restrict__ bkt, const int* __restrict__ gcur,
                            uint32_t* __restrict__ csr, int* __restrict__ row,
                            int* __restrict__ cnt) {
    __shared__ int h[512];
    __shared__ int cur[512];
    __shared__ int sd[512];
    const int b = blockIdx.x, tid = threadIdx.x;
    int n = gcur[b]; n = n > BCAP ? BCAP : n;
    const uint32_t* eb = bkt + size_t(b) * BCAP;
    h[tid] = 0;
    __syncthreads();
    for (int i = tid; i < n; i += 512) atomicAdd(&h[eb[i] & 511u], 1);
    __syncthreads();
    const int a0 = h[tid];
    sd[tid] = a0;
    __syncthreads();
    for (int off = 1; off < 512; off <<= 1) {
        int t = (tid >= off) ? sd[tid - off] : 0;
        __syncthreads();
        sd[tid] += t;
        __syncthreads();
    }
    const int base = sd[tid] - a0;     // exclusive prefix
    cur[tid] = base;
    const int node = b * 512 + tid;
    if (node < N_NODES) {
        row[node] = b * BCAP + base;
        cnt[node] = a0;
    }
    __syncthreads();
    uint32_t* cb = csr + size_t(b) * BCAP;
    for (int i = tid; i < n; i += 512) {
        uint32_t e = eb[i];
        int p = atomicAdd(&cur[e & 511u], 1);
        cb[p] = e >> 9;
    }
}

// ---- aggregation: out[i] = x[i] + sum_{j->i} x[j]  (bf16 in/out, fp32 acc) -
// Neighbor loop unrolled x8 with independent loads -> 8x memory-level
// parallelism. No LDS: occupancy is the gather's lifeblood (R8 lesson).
template <int D>
__global__ void gin_aggregate(const uint16_t* __restrict__ xb, const int* __restrict__ row,
                              const int* __restrict__ cnt, const uint32_t* __restrict__ csr,
                              uint16_t* __restrict__ out) {
    constexpr int TPN = D / 8;                 // lanes per node (16B bf16 each)
    const int tid  = threadIdx.x;
    const int node = blockIdx.x * (256 / TPN) + tid / TPN;
    const int lane = tid % TPN;
    if (node >= N_NODES) return;
    const size_t off   = size_t(lane) * 8;
    const size_t rbase = size_t(node) * D + off;
    uint4 v = *reinterpret_cast<const uint4*>(&xb[rbase]);
    float a[8];
    unpack2(v.x, a[0], a[1]); unpack2(v.y, a[2], a[3]);
    unpack2(v.z, a[4], a[5]); unpack2(v.w, a[6], a[7]);
    const int c = cnt[node];
    const uint32_t* sl = csr + row[node];
    int p = 0;
    for (; p + 8 <= c; p += 8) {
        uint4 w0 = *reinterpret_cast<const uint4*>(&xb[size_t(sl[p + 0]) * D + off]);
        uint4 w1 = *reinterpret_cast<const uint4*>(&xb[size_t(sl[p + 1]) * D + off]);
        uint4 w2 = *reinterpret_cast<const uint4*>(&xb[size_t(sl[p + 2]) * D + off]);
        uint4 w3 = *reinterpret_cast<const uint4*>(&xb[size_t(sl[p + 3]) * D + off]);
        uint4 w4 = *reinterpret_cast<const uint4*>(&xb[size_t(sl[p + 4]) * D + off]);
        uint4 w5 = *reinterpret_cast<const uint4*>(&xb[size_t(sl[p + 5]) * D + off]);
        uint4 w6 = *reinterpret_cast<const uint4*>(&xb[size_t(sl[p + 6]) * D + off]);
        uint4 w7 = *reinterpret_cast<const uint4*>(&xb[size_t(sl[p + 7]) * D + off]);
        accum8(a, w0); accum8(a, w1); accum8(a, w2); accum8(a, w3);
        accum8(a, w4); accum8(a, w5); accum8(a, w6); accum8(a, w7);
    }
    for (; p < c; ++p) {
        uint4 w = *reinterpret_cast<const uint4*>(&xb[size_t(sl[p]) * D + off]);
        accum8(a, w);
    }
    uint4 o = make_uint4(pack2(a[0], a[1]), pack2(a[2], a[3]),
                         pack2(a[4], a[5]), pack2(a[6], a[7]));
    *reinterpret_cast<uint4*>(&out[rbase]) = o;
}

// ---- fused conv MLP: relu( relu(A@Wa + ba) @ Wb + bb ) ---------------------
// A[M,K1] bf16 row-major; Wa as WTa[n][k]; intermediate 128x128 bf16 tile in
// LDS between the two GEMMs. POOL=false: coalesced stores to out.
// POOL=true: per-row dot(Wc) + 16-lane shfl reduce -> LDS rowdot ->
// per-graph LDS reduce (batch sorted: block spans ~2 graphs) -> ~2-3 global
// atomics per block (100k global fp32 atomics on 32 lines serialize; R10).
// launch_bounds(256,3): (256,4) caps VGPR at 64 -> scratch spill (R9/R10).
typedef __attribute__((ext_vector_type(8))) short short8;
typedef __attribute__((ext_vector_type(4))) float f32x4;

template <int K1, bool POOL>
__launch_bounds__(256, 3)
__global__ void gin_mlp(const uint16_t* __restrict__ A, const uint16_t* __restrict__ WTa,
                        const float* __restrict__ ba, const uint16_t* __restrict__ WTb,
                        const float* __restrict__ bb, uint16_t* __restrict__ out,
                        const void* __restrict__ bat, const int* __restrict__ flag,
                        const float* __restrict__ Wc, float* __restrict__ pacc,
                        int M) {
    constexpr int TSTR = 136;                       // +8 halfword pad
    __shared__ uint16_t tile[128 * TSTR];           // 34 KB
    const int tid  = threadIdx.x;
    const int wave = tid >> 6;
    const int lane = tid & 63;
    const int lr   = lane & 15;
    const int q    = lane >> 4;
    const int bnode0 = blockIdx.x * 128;
    const int m_base = bnode0 + wave * 32;
    const int trow   = wave * 32 + q * 4;           // first output row (local)

    // ---- GEMM1: A @ WTa -> tile (bias ba, relu) ----
    short8 afr1[2][K1 / 32];
    #pragma unroll
    for (int mt = 0; mt < 2; ++mt) {
        int row = m_base + mt * 16 + lr;
        row = row < M ? row : (M - 1);
        const uint16_t* ap = A + size_t(row) * K1 + q * 8;
        #pragma unroll
        for (int kb = 0; kb < K1 / 32; ++kb)
            afr1[mt][kb] = *reinterpret_cast<const short8*>(ap + kb * 32);
    }
    for (int nt = 0; nt < 8; ++nt) {
        const uint16_t* bp = WTa + size_t(nt * 16 + lr) * K1 + q * 8;
        f32x4 c0 = {0.f, 0.f, 0.f, 0.f};
        f32x4 c1 = {0.f, 0.f, 0.f, 0.f};
        #pragma unroll
        for (int kb = 0; kb < K1 / 32; ++kb) {
            short8 b = *reinterpret_cast<const short8*>(bp + kb * 32);
            c0 = __builtin_amdgcn_mfma_f32_16x16x32_bf16(afr1[0][kb], b, c0, 0, 0, 0);
            c1 = __builtin_amdgcn_mfma_f32_16x16x32_bf16(afr1[1][kb], b, c1, 0, 0, 0);
        }
        const float bv = ba[nt * 16 + lr];
        const int col = nt * 16 + lr;
        #pragma unroll
        for (int r = 0; r < 4; ++r) {
            float v0 = fmaxf(c0[r] + bv, 0.f);
            float v1 = fmaxf(c1[r] + bv, 0.f);
            tile[(trow + r) * TSTR + col]      = f32_to_bf16(v0);
            tile[(trow + 16 + r) * TSTR + col] = f32_to_bf16(v1);
        }
    }
    __syncthreads();

    // ---- A-fragments for GEMM2 from LDS tile ----
    short8 afr2[2][4];
    #pragma unroll
    for (int mt = 0; mt < 2; ++mt) {
        const int r = wave * 32 + mt * 16 + lr;
        #pragma unroll
        for (int kb = 0; kb < 4; ++kb)
            afr2[mt][kb] = *reinterpret_cast<const short8*>(
                &tile[r * TSTR + kb * 32 + q * 8]);
    }
    __syncthreads();   // tile is dead after this; reused below

    // ---- GEMM2 (bias bb, relu) ----
    if (!POOL) {
        for (int nt = 0; nt < 8; ++nt) {
            const uint16_t* bp = WTb + size_t(nt * 16 + lr) * 128 + q * 8;
            f32x4 c0 = {0.f, 0.f, 0.f, 0.f};
            f32x4 c1 = {0.f, 0.f, 0.f, 0.f};
            #pragma unroll
            for (int kb = 0; kb < 4; ++kb) {
                short8 b = *reinterpret_cast<const short8*>(bp + kb * 32);
                c0 = __builtin_amdgcn_mfma_f32_16x16x32_bf16(afr2[0][kb], b, c0, 0, 0, 0);
                c1 = __builtin_amdgcn_mfma_f32_16x16x32_bf16(afr2[1][kb], b, c1, 0, 0, 0);
            }
            const float bv = bb[nt * 16 + lr];
            const int col = nt * 16 + lr;
            #pragma unroll
            for (int r = 0; r < 4; ++r) {
                float v0 = fmaxf(c0[r] + bv, 0.f);
                float v1 = fmaxf(c1[r] + bv, 0.f);
                tile[(trow + r) * TSTR + col]      = f32_to_bf16(v0);
                tile[(trow + 16 + r) * TSTR + col] = f32_to_bf16(v1);
            }
        }
        __syncthreads();
        // coalesced vectorized stores: 16 threads per row, 16B each
        const int c8 = (tid & 15) * 8;
        for (int rr = tid >> 4; rr < 128; rr += 16) {
            int grow = bnode0 + rr;
            if (grow < M)
                *reinterpret_cast<uint4*>(&out[size_t(grow) * 128 + c8]) =
                    *reinterpret_cast<const uint4*>(&tile[rr * TSTR + c8]);
        }
    } else {
        // block-level pooled reduction (tile memory reused as fp32 scratch)
        float* rowdot = reinterpret_cast<float*>(tile);        // [0..128)
        float* gacc   = rowdot + 128;                          // [128..256)
        if (tid < 128) gacc[tid] = 0.f;

        float pd0[4] = {0.f, 0.f, 0.f, 0.f};
        float pd1[4] = {0.f, 0.f, 0.f, 0.f};
        for (int nt = 0; nt < 8; ++nt) {
            const uint16_t* bp = WTb + size_t(nt * 16 + lr) * 128 + q * 8;
            f32x4 c0 = {0.f, 0.f, 0.f, 0.f};
            f32x4 c1 = {0.f, 0.f, 0.f, 0.f};
            #pragma unroll
            for (int kb = 0; kb < 4; ++kb) {
                short8 b = *reinterpret_cast<const short8*>(bp + kb * 32);
                c0 = __builtin_amdgcn_mfma_f32_16x16x32_bf16(afr2[0][kb], b, c0, 0, 0, 0);
                c1 = __builtin_amdgcn_mfma_f32_16x16x32_bf16(afr2[1][kb], b, c1, 0, 0, 0);
            }
            const int col = nt * 16 + lr;
            const float bv = bb[col];
            const float wv = Wc[col];
            #pragma unroll
            for (int r = 0; r < 4; ++r) {
                pd0[r] += fmaxf(c0[r] + bv, 0.f) * wv;
                pd1[r] += fmaxf(c1[r] + bv, 0.f) * wv;
            }
        }
        #pragma unroll
        for (int m = 1; m < 16; m <<= 1) {
            #pragma unroll
            for (int r = 0; r < 4; ++r) {
                pd0[r] += __shfl_xor(pd0[r], m, 64);
                pd1[r] += __shfl_xor(pd1[r], m, 64);
            }
        }
        if (lr == 0) {
            #pragma unroll
            for (int r = 0; r < 4; ++r) {
                rowdot[trow + r]      = pd0[r];
                rowdot[trow + 16 + r] = pd1[r];
            }
        }
        __syncthreads();

        const bool wide = (*flag == 0);
        const int g0 = load_idx(bat, size_t(bnode0 < M ? bnode0 : M - 1), wide);
        if (tid < 128) {
            int node = bnode0 + tid;
            if (node < M) {
                int g = load_idx(bat, size_t(node), wide);
                int idx = g - g0;
                if (idx < 128) atomicAdd(&gacc[idx], rowdot[tid]);
                else           atomicAdd(&pacc[g], rowdot[tid]);   // gap fallback
            }
        }
        __syncthreads();
        int last = bnode0 + 127 < M ? bnode0 + 127 : M - 1;
        int span = load_idx(bat, size_t(last), wide) - g0;
        if (span > 127) span = 127;
        if (tid <= span) {
            float v = gacc[tid];
            if (v != 0.f) atomicAdd(&pacc[g0 + tid], v);
        }
    }
}

// ---- finalize: out[g] = pacc[g]/max(count,1) + bc --------------------------
__global__ void finalize(const float* __restrict__ pacc, const int* __restrict__ goff,
                         const float* __restrict__ bc, float* __restrict__ out) {
    int g = blockIdx.x * 256 + threadIdx.x;
    if (g >= N_GRAPHS) return;
    int c = goff[g + 1] - goff[g];
    float denom = (c > 0) ? (float)c : 1.f;
    out[g] = pacc[g] / denom + bc[0];
}

}  // namespace

extern "C" void kernel_launch(void* const* d_in, const int* in_sizes, int n_in,
                              void* d_out, int out_size, void* d_ws, size_t ws_size,
                              hipStream_t stream) {
    (void)in_sizes; (void)n_in; (void)out_size;
    if (ws_size < WS_NEED) return;

    const float* x   = (const float*)d_in[0];
    const void*  ei  = d_in[1];
    const void*  bat = d_in[2];
    const float* W1a = (const float*)d_in[3];
    const float* b1a = (const float*)d_in[4];
    const float* W1b = (const float*)d_in[5];
    const float* b1b = (const float*)d_in[6];
    const float* W2a = (const float*)d_in[7];
    const float* b2a = (const float*)d_in[8];
    const float* W2b = (const float*)d_in[9];
    const float* b2b = (const float*)d_in[10];
    const float* Wc  = (const float*)d_in[11];
    const float* bc  = (const float*)d_in[12];
    float* out = (float*)d_out;

    char* ws = (char*)d_ws;
    int*      cnt  = (int*)(ws + OFF_CNT);
    int*      row  = (int*)(ws + OFF_ROW);
    int*      goff = (int*)(ws + OFF_GOFF);
    int*      flg  = (int*)(ws + OFF_FLAG);
    int*      gcur = (int*)(ws + OFF_GCUR);
    float*    pacc = (float*)(ws + OFF_PACC);
    uint32_t* bkt  = (uint32_t*)(ws + OFF_BKT);
    uint32_t* csr  = (uint32_t*)(ws + OFF_CSR);
    uint16_t* xb   = (uint16_t*)(ws + OFF_XB);
    uint16_t* T1a  = (uint16_t*)(ws + OFF_WT1A);
    uint16_t* T1b  = (uint16_t*)(ws + OFF_WT1B);
    uint16_t* T2a  = (uint16_t*)(ws + OFF_WT2A);
    uint16_t* T2b  = (uint16_t*)(ws + OFF_WT2B);
    uint16_t* F0   = (uint16_t*)(ws + OFF_F0);
    uint16_t* H1   = (uint16_t*)(ws + OFF_H1);
    uint16_t* H2   = (uint16_t*)(ws + OFF_H2);

    detect_wide<<<1, 256, 0, stream>>>((const int*)ei, flg, gcur, pacc);

    // fused prep: bucket + cvt_x + cvt_weights + goff
    prep<<<PB_TOTAL, 256, 0, stream>>>(ei, bat, flg, x, W1a, W1b, W2a, W2b,
                                       gcur, bkt, xb, T1a, T1b, T2a, T2b, goff);
    sort_bucket<<<NBUCK, 512, 0, stream>>>(bkt, gcur, csr, row, cnt);

    constexpr int GRID = (N_NODES + 127) / 128;   // 782

    // conv1
    gin_aggregate<64><<<(N_NODES + 31) / 32, 256, 0, stream>>>(xb, row, cnt, csr, F0);
    gin_mlp<64, false><<<GRID, 256, 0, stream>>>(F0, T1a, b1a, T1b, b1b, H1,
                                                 bat, flg, Wc, pacc, N_NODES);
    // conv2 (MLP fuses mean-pool via block-level reduction)
    gin_aggregate<128><<<(N_NODES + 15) / 16, 256, 0, stream>>>(H1, row, cnt, csr, H2);
    gin_mlp<128, true><<<GRID, 256, 0, stream>>>(H2, T2a, b2a, T2b, b2b, H1,
                                                 bat, flg, Wc, pacc, N_NODES);
    // head
    finalize<<<2, 256, 0, stream>>>(pacc, goff, bc, out);
}